// Round 18
// baseline (136.688 us; speedup 1.0000x reference)
//
#include <hip/hip_runtime.h>
#include <math.h>

typedef unsigned short ushort_t;
typedef __attribute__((ext_vector_type(8))) __bf16 bf16x8;
typedef __attribute__((ext_vector_type(4))) float floatx4;

#define B_    256
#define I_    1152
#define J_    10
#define DIN_  8
#define DOUT_ 16
#define K_    (I_*DIN_)     // 9216
#define N_    (J_*DOUT_)    // 160
#define KSPLIT 16           // packed k-chunks per output tile (layout unit)
#define KCHUNK (K_/KSPLIT)  // 576
#define KSTEPS (KCHUNK/32)  // 18
#define CHUNK16 2368        // 37KB packed chunk stride in 16B units

static __device__ __forceinline__ ushort_t f2bf(float f) {
    unsigned int u = __float_as_uint(f);
    u += 0x7fffu + ((u >> 16) & 1u);     // RNE
    return (ushort_t)(u >> 16);
}
static __device__ __forceinline__ float bf2f(ushort_t h) {
    return __uint_as_float(((unsigned int)h) << 16);
}
// Relaxed agent-scope (LLC) atomics — r10/r13-validated for cross-block
// handoff without fences; cheap at this volume (1.3 MB pbuf + 160 tickets).
static __device__ __forceinline__ void ast_f(float* p, float v) {
    __hip_atomic_store(p, v, __ATOMIC_RELAXED, __HIP_MEMORY_SCOPE_AGENT);
}
static __device__ __forceinline__ float ald_f(const float* p) {
    return __hip_atomic_load(p, __ATOMIC_RELAXED, __HIP_MEMORY_SCOPE_AGENT);
}

// ---------------------------------------------------------------------------
// prep_all (r11 verbatim + ticket zeroing in block 0 — saves a memset
// dispatch; kernel-boundary release makes the zeros visible to AB0).
// ---------------------------------------------------------------------------
__global__ __launch_bounds__(256)
void prep_all_kernel(const float* __restrict__ x, const float* __restrict__ W,
                     ushort_t* __restrict__ xPk, float* __restrict__ wPk,
                     unsigned int* __restrict__ cnt)
{
    const int blk = blockIdx.x;
    const int tid = threadIdx.x;

    if (blk == 0) {
        for (int i = tid; i < 480; i += 256) cnt[i] = 0u;
    }

    if (blk < 1152) {
        const int gid = blk * 256 + tid;
        const int f   = gid * 8;
        const int row = f / K_;
        const int kk  = f - row * K_;
        const int kc  = kk / KCHUNK;
        const int t   = kk - kc * KCHUNK;
        const int s   = t >> 5;
        const int q   = (t & 31) >> 3;
        const int mb  = row >> 4, r = row & 15;

        const float* src = x + (size_t)f;
        bf16x8 h8, l8;
        #pragma unroll
        for (int e = 0; e < 8; ++e) {
            float v = src[e];
            __bf16 h = (__bf16)v;
            h8[e] = h;
            l8[e] = (__bf16)(v - (float)h);
        }
        bf16x8* dst = (bf16x8*)xPk + (size_t)(mb * 16 + kc) * CHUNK16 + s * 128 + q * 16 + r;
        dst[0]  = h8;
        dst[64] = l8;
    } else {
        const int gid = (blk - 1152) * 256 + tid;
        const int f   = gid * 4;
        const int i   = f / 1280;
        const int rem = f - i * 1280;
        const int no  = rem >> 3;
        const int p   = (rem >> 2) & 1;
        const int nt  = no >> 4, r = no & 15;
        const int kc  = i / 72;
        const int m   = i - kc * 72;
        const int s   = m >> 2, q = m & 3;
        float4 v = *(const float4*)(W + (size_t)f);
        ((float4*)wPk)[(size_t)(nt * 16 + kc) * CHUNK16 + (s * 2 + p) * 64 + q * 16 + r] = v;
    }
}

// ---------------------------------------------------------------------------
// AB: s-GEMM partials + in-kernel reduce/squash/emit. Body = r11's A
// verbatim (session-best kernel); epilogue = r13's ticket mechanism
// (passed, absmax 0.00390625): LLC partial store -> __syncthreads (vmcnt
// drain) -> ticket atomicAdd; 8th-arriving block per tile sums the 8
// k-slice partials (r11 reduce order), squashes, emits. Saves one kernel
// boundary (~6us, cross-round fit) per iteration at ~2-3us ticket cost.
// ---------------------------------------------------------------------------
__global__ __launch_bounds__(256)
void gemm_s_ab_kernel(const ushort_t* __restrict__ xPk, const float* __restrict__ wPk,
                      const float* __restrict__ blog,
                      float* __restrict__ pbuf_it, unsigned int* __restrict__ cnt_it,
                      float* __restrict__ s_out,
                      ushort_t* __restrict__ Sbt_hi, ushort_t* __restrict__ Sbt_lo,
                      const int iter)
{
    const int tid   = threadIdx.x;         // 0..255
    const int blk   = blockIdx.x;          // 0..1279
    const int kb    = blk & 7;             // K-slice / XCD heuristic
    const int tile  = blk >> 3;            // 0..159
    const int mb    = tile & 15;
    const int nt    = tile >> 4;
    const int lane  = tid & 63;
    const int w     = tid >> 6;            // 0..3
    const int kc    = kb * 2 + (w >> 1);   // chunk of this wave pair
    const int shalf = w & 1;               // 9-step half within the chunk

    __shared__ float   c_lds[144];
    __shared__ floatx4 part[4 * 64];
    __shared__ int     last_s;

    if (iter > 0) {
        for (int r2 = tid; r2 < 144; r2 += 256) {
            const float* br = blog + (size_t)(kb * 144 + r2) * J_;
            float bv[J_];
            float mx = -1e30f;
            #pragma unroll
            for (int j = 0; j < J_; ++j) { bv[j] = br[j]; mx = fmaxf(mx, bv[j]); }
            float sum = 0.f;
            #pragma unroll
            for (int j = 0; j < J_; ++j) { bv[j] = __expf(bv[j] - mx); sum += bv[j]; }
            c_lds[r2] = bv[nt] / sum;
        }
        __syncthreads();
    }

    {
        const int q = lane >> 4;
        const int sbase = shalf * 9;       // global step offset of this wave
        const bf16x8* xp = (const bf16x8*)xPk + (size_t)(mb * 16 + kc) * CHUNK16
                           + sbase * 128 + lane;
        const float4* wp = (const float4*)wPk + (size_t)(nt * 16 + kc) * CHUNK16
                           + sbase * 128 + lane;
        floatx4 acc = {0.f, 0.f, 0.f, 0.f};

        // 2-deep prefetch ring over 9 steps
        bf16x8 rah[2], ral[2];
        float4 rw0[2], rw1[2];
        #pragma unroll
        for (int s = 0; s < 2; ++s) {
            rah[s] = xp[s * 128];
            ral[s] = xp[s * 128 + 64];
            rw0[s] = wp[s * 128];
            rw1[s] = wp[s * 128 + 64];
        }
        #pragma unroll
        for (int s = 0; s < 9; ++s) {
            bf16x8 ah = rah[s & 1], al = ral[s & 1];
            float4 w0 = rw0[s & 1], w1 = rw1[s & 1];
            if (s + 2 < 9) {
                rah[s & 1] = xp[(s + 2) * 128];
                ral[s & 1] = xp[(s + 2) * 128 + 64];
                rw0[s & 1] = wp[(s + 2) * 128];
                rw1[s & 1] = wp[(s + 2) * 128 + 64];
            }
            float cs = (iter == 0) ? 0.1f
                                   : c_lds[(w >> 1) * 72 + 4 * (sbase + s) + q];
            float wvv[8] = {w0.x, w0.y, w0.z, w0.w, w1.x, w1.y, w1.z, w1.w};
            bf16x8 bh, bl;
            #pragma unroll
            for (int e = 0; e < 8; ++e) {
                float pe = wvv[e] * cs;
                __bf16 g = (__bf16)pe;
                bh[e] = g;
                bl[e] = (__bf16)(pe - (float)g);
            }
            acc = __builtin_amdgcn_mfma_f32_16x16x32_bf16(ah, bh, acc, 0, 0, 0);
            acc = __builtin_amdgcn_mfma_f32_16x16x32_bf16(al, bh, acc, 0, 0, 0);
            acc = __builtin_amdgcn_mfma_f32_16x16x32_bf16(ah, bl, acc, 0, 0, 0);
        }
        part[w * 64 + lane] = acc;
    }
    __syncthreads();

    // ---- in-block 4-wave reduce -> LLC partial store (r13 epilogue) ----
    const int row = tid >> 4;              // 0..15 (b_local)
    const int o   = tid & 15;              // 0..15
    const int lane_c = ((row >> 2) << 4) | o;   // C/D: col=lane&15, row=quad*4+reg
    const int reg    = row & 3;
    float v = part[0 * 64 + lane_c][reg] + part[1 * 64 + lane_c][reg]
            + part[2 * 64 + lane_c][reg] + part[3 * 64 + lane_c][reg];
    ast_f(pbuf_it + (size_t)(tile * 8 + kb) * 256 + row * 16 + o, v);
    __syncthreads();                       // drain stores (vmcnt) pre-ticket
    if (tid == 0)
        last_s = (atomicAdd(cnt_it + tile, 1u) == 7u);
    __syncthreads();
    if (!last_s) return;

    // ---- last arrival: sum 8 k-slice partials (r11 order), squash, emit ----
    const float* pb = pbuf_it + (size_t)tile * 8 * 256 + row * 16 + o;
    float vv = 0.f;
    #pragma unroll
    for (int u = 0; u < 8; ++u)
        vv += ald_f(pb + u * 256);
    float sq = vv * vv;
    #pragma unroll
    for (int off = 1; off < 16; off <<= 1)  // 16 consecutive lanes = one b row
        sq += __shfl_xor(sq, off, 16);
    float l2 = sqrtf(sq);
    float val = vv * (l2 / (1.f + sq));
    const int b  = mb * 16 + row;
    const int jo = nt * 16 + o;
    if (iter == 2) {
        s_out[(size_t)b * N_ + jo] = val;
    } else {
        ushort_t hi = f2bf(val);
        Sbt_hi[(size_t)jo * B_ + b] = hi;
        Sbt_lo[(size_t)jo * B_ + b] = f2bf(val - bf2f(hi));
    }
}

// ---------------------------------------------------------------------------
// C: b-update GEMM (r5/r7/r11 verbatim — plain loads/stores only).
// ---------------------------------------------------------------------------
__global__ __launch_bounds__(256)
void gemm_bupd_kernel(const float* __restrict__ x,
                      const ushort_t* __restrict__ Sbt_hi, const ushort_t* __restrict__ Sbt_lo,
                      const float* __restrict__ W, float* __restrict__ blog,
                      const int first)
{
    // bijective remap: XCD (blk&7) gets wv in [xcd*360, xcd*360+360) -> mt
    // in [xcd*72, xcd*72+72) contiguous (720 blocks, 720%8==0).
    int wv   = (blockIdx.x & 7) * 360 + (blockIdx.x >> 3) * 4 + (threadIdx.x >> 6);
    int lane = threadIdx.x & 63;
    int mt = wv / 5;                                  // 0..575
    int jp = wv - mt * 5;                             // j-pair: j0=2jp, j1=2jp+1
    int j0 = jp * 2, j1 = jp * 2 + 1;
    int r = lane & 15, q = lane >> 4;
    const float* xp = x + (size_t)(8 * q) * K_ + (mt * 16 + r);   // + (s*32+e)*K_
    size_t b0off = (size_t)(j0 * 16 + r) * B_ + 8 * q;
    size_t b1off = (size_t)(j1 * 16 + r) * B_ + 8 * q;
    floatx4 acc0 = {0.f, 0.f, 0.f, 0.f};
    floatx4 acc1 = {0.f, 0.f, 0.f, 0.f};

    float xcur[8], xnxt[8];
    #pragma unroll
    for (int e = 0; e < 8; ++e) xcur[e] = xp[(size_t)e * K_];
    #pragma unroll
    for (int s = 0; s < B_ / 32; ++s) {
        if (s + 1 < B_ / 32) {               // prefetch next step's x column slice
            #pragma unroll
            for (int e = 0; e < 8; ++e)
                xnxt[e] = xp[(size_t)((s + 1) * 32 + e) * K_];
        }
        bf16x8 ah, al;
        #pragma unroll
        for (int e = 0; e < 8; ++e) {
            float v = xcur[e];
            __bf16 h = (__bf16)v;
            ah[e] = h;
            al[e] = (__bf16)(v - (float)h);
        }
        bf16x8 bh0 = *(const bf16x8*)(Sbt_hi + b0off + s * 32);
        bf16x8 bl0 = *(const bf16x8*)(Sbt_lo + b0off + s * 32);
        bf16x8 bh1 = *(const bf16x8*)(Sbt_hi + b1off + s * 32);
        bf16x8 bl1 = *(const bf16x8*)(Sbt_lo + b1off + s * 32);
        acc0 = __builtin_amdgcn_mfma_f32_16x16x32_bf16(ah, bh0, acc0, 0, 0, 0);
        acc0 = __builtin_amdgcn_mfma_f32_16x16x32_bf16(al, bh0, acc0, 0, 0, 0);
        acc0 = __builtin_amdgcn_mfma_f32_16x16x32_bf16(ah, bl0, acc0, 0, 0, 0);
        acc1 = __builtin_amdgcn_mfma_f32_16x16x32_bf16(ah, bh1, acc1, 0, 0, 0);
        acc1 = __builtin_amdgcn_mfma_f32_16x16x32_bf16(al, bh1, acc1, 0, 0, 0);
        acc1 = __builtin_amdgcn_mfma_f32_16x16x32_bf16(ah, bl1, acc1, 0, 0, 0);
        #pragma unroll
        for (int e = 0; e < 8; ++e) xcur[e] = xnxt[e];
    }
    // rows q*4+reg -> i = mt*2 + (q>>1), d = (q&1)*4 + reg; col -> o = lane&15
    int i  = mt * 2 + (q >> 1);
    int d0 = (q & 1) * 4;
    int o  = lane & 15;
    int iw = mt * 2 + (lane >> 5);
    {
        const float4 w4 = *(const float4*)(W + ((((size_t)i * J_ + j0) * DOUT_ + o) * DIN_ + d0));
        float val = acc0[0] * w4.x + acc0[1] * w4.y + acc0[2] * w4.z + acc0[3] * w4.w;
        #pragma unroll
        for (int off = 1; off < 32; off <<= 1)
            val += __shfl_xor(val, off, 32);
        if ((lane & 31) == 0) {
            float* dst = blog + (size_t)iw * J_ + j0;
            if (first) *dst = val; else *dst += val;
        }
    }
    {
        const float4 w4 = *(const float4*)(W + ((((size_t)i * J_ + j1) * DOUT_ + o) * DIN_ + d0));
        float val = acc1[0] * w4.x + acc1[1] * w4.y + acc1[2] * w4.z + acc1[3] * w4.w;
        #pragma unroll
        for (int off = 1; off < 32; off <<= 1)
            val += __shfl_xor(val, off, 32);
        if ((lane & 31) == 0) {
            float* dst = blog + (size_t)iw * J_ + j1;
            if (first) *dst = val; else *dst += val;
        }
    }
}

// ---------------------------------------------------------------------------
// 6-dispatch chain (was 9): prep(+cnt zero), AB0, C0, AB1, C1, AB2.
// ---------------------------------------------------------------------------
extern "C" void kernel_launch(void* const* d_in, const int* in_sizes, int n_in,
                              void* d_out, int out_size, void* d_ws, size_t ws_size,
                              hipStream_t stream)
{
    const float* x = (const float*)d_in[0];   // [B, I, DIN]
    const float* W = (const float*)d_in[1];   // [I, J, DOUT, DIN]
    float* s_out = (float*)d_out;             // [B, J, DOUT]

    char* ws = (char*)d_ws;
    ushort_t*     Sbt_hi = (ushort_t*)(ws);                 //    81,920 B
    ushort_t*     Sbt_lo = (ushort_t*)(ws + 81920);         //    81,920 B
    float*        blog   = (float*)   (ws + 163840);        //    46,080 B
    float*        pbuf   = (float*)   (ws + 262144);        // 3,932,160 B (3 iters)
    unsigned int* cnt    = (unsigned int*)(ws + 4194304);   //     1,920 B
    ushort_t*     xPk    = (ushort_t*)(ws + 4196352);       // 9,699,328 B
    float*        wPk    = (float*)   (ws + 13895680);      // 6,062,080 B (~20 MB)

    prep_all_kernel<<<2592, 256, 0, stream>>>(x, W, xPk, wPk, cnt);

    for (int it = 0; it < 3; ++it) {
        gemm_s_ab_kernel<<<1280, 256, 0, stream>>>(xPk, wPk, blog,
                                                   pbuf + (size_t)it * 327680,
                                                   cnt + it * 160,
                                                   s_out, Sbt_hi, Sbt_lo, it);
        if (it < 2)
            gemm_bupd_kernel<<<720, 256, 0, stream>>>(x, Sbt_hi, Sbt_lo,
                                                      W, blog, it == 0 ? 1 : 0);
    }
}

// Round 19
// 134.820 us; speedup vs baseline: 1.0139x; 1.0139x over previous
//
#include <hip/hip_runtime.h>
#include <math.h>

typedef unsigned short ushort_t;
typedef __attribute__((ext_vector_type(8))) __bf16 bf16x8;
typedef __attribute__((ext_vector_type(4))) float floatx4;

#define B_    256
#define I_    1152
#define J_    10
#define DIN_  8
#define DOUT_ 16
#define K_    (I_*DIN_)     // 9216
#define N_    (J_*DOUT_)    // 160
#define KSPLIT 16           // packed k-chunks per output tile (layout unit)
#define KCHUNK (K_/KSPLIT)  // 576
#define KSTEPS (KCHUNK/32)  // 18
#define CHUNK16 2368        // 37KB packed chunk stride in 16B units

static __device__ __forceinline__ ushort_t f2bf(float f) {
    unsigned int u = __float_as_uint(f);
    u += 0x7fffu + ((u >> 16) & 1u);     // RNE
    return (ushort_t)(u >> 16);
}
static __device__ __forceinline__ float bf2f(ushort_t h) {
    return __uint_as_float(((unsigned int)h) << 16);
}

// ---------------------------------------------------------------------------
// prep_all (ONE dispatch): xpack + wpack.
//   xPk: fragment-major Dekker bf16 hi/lo planes (bit-identical splits).
//   wPk: fragment-major fp32 permuted copy.
// ---------------------------------------------------------------------------
__global__ __launch_bounds__(256)
void prep_all_kernel(const float* __restrict__ x, const float* __restrict__ W,
                     ushort_t* __restrict__ xPk, float* __restrict__ wPk)
{
    const int blk = blockIdx.x;
    const int tid = threadIdx.x;

    if (blk < 1152) {
        const int gid = blk * 256 + tid;
        const int f   = gid * 8;
        const int row = f / K_;
        const int kk  = f - row * K_;
        const int kc  = kk / KCHUNK;
        const int t   = kk - kc * KCHUNK;
        const int s   = t >> 5;
        const int q   = (t & 31) >> 3;
        const int mb  = row >> 4, r = row & 15;

        const float* src = x + (size_t)f;
        bf16x8 h8, l8;
        #pragma unroll
        for (int e = 0; e < 8; ++e) {
            float v = src[e];
            __bf16 h = (__bf16)v;
            h8[e] = h;
            l8[e] = (__bf16)(v - (float)h);
        }
        bf16x8* dst = (bf16x8*)xPk + (size_t)(mb * 16 + kc) * CHUNK16 + s * 128 + q * 16 + r;
        dst[0]  = h8;
        dst[64] = l8;
    } else {
        const int gid = (blk - 1152) * 256 + tid;
        const int f   = gid * 4;
        const int i   = f / 1280;
        const int rem = f - i * 1280;
        const int no  = rem >> 3;
        const int p   = (rem >> 2) & 1;
        const int nt  = no >> 4, r = no & 15;
        const int kc  = i / 72;
        const int m   = i - kc * 72;
        const int s   = m >> 2, q = m & 3;
        float4 v = *(const float4*)(W + (size_t)f);
        ((float4*)wPk)[(size_t)(nt * 16 + kc) * CHUNK16 + (s * 2 + p) * 64 + q * 16 + r] = v;
    }
}

// ---------------------------------------------------------------------------
// A: s-GEMM partials — session-best kernel. 1280 blocks x 256 thr (4 waves).
// Wave pair (w>>1) owns k-chunk kc = kb*2 + (w>>1); waves of a pair split
// its 18 steps into two 9-step halves. 5120 waves = 5/SIMD. In-block 4-wave
// reduce -> plain pbuf store. No fences/atomics.
// ---------------------------------------------------------------------------
__global__ __launch_bounds__(256)
void gemm_s_part_kernel(const ushort_t* __restrict__ xPk, const float* __restrict__ wPk,
                        const float* __restrict__ blog,
                        float* __restrict__ pbuf, const int iter)
{
    const int tid   = threadIdx.x;         // 0..255
    const int blk   = blockIdx.x;          // 0..1279
    const int kb    = blk & 7;             // K-slice / XCD heuristic
    const int tile  = blk >> 3;            // 0..159
    const int mb    = tile & 15;
    const int nt    = tile >> 4;
    const int lane  = tid & 63;
    const int w     = tid >> 6;            // 0..3
    const int kc    = kb * 2 + (w >> 1);   // chunk of this wave pair
    const int shalf = w & 1;               // 9-step half within the chunk

    __shared__ float   c_lds[144];
    __shared__ floatx4 part[4 * 64];

    if (iter > 0) {
        for (int r2 = tid; r2 < 144; r2 += 256) {
            const float* br = blog + (size_t)(kb * 144 + r2) * J_;
            float bv[J_];
            float mx = -1e30f;
            #pragma unroll
            for (int j = 0; j < J_; ++j) { bv[j] = br[j]; mx = fmaxf(mx, bv[j]); }
            float sum = 0.f;
            #pragma unroll
            for (int j = 0; j < J_; ++j) { bv[j] = __expf(bv[j] - mx); sum += bv[j]; }
            c_lds[r2] = bv[nt] / sum;
        }
        __syncthreads();
    }

    {
        const int q = lane >> 4;
        const int sbase = shalf * 9;       // global step offset of this wave
        const bf16x8* xp = (const bf16x8*)xPk + (size_t)(mb * 16 + kc) * CHUNK16
                           + sbase * 128 + lane;
        const float4* wp = (const float4*)wPk + (size_t)(nt * 16 + kc) * CHUNK16
                           + sbase * 128 + lane;
        floatx4 acc = {0.f, 0.f, 0.f, 0.f};

        // 2-deep prefetch ring over 9 steps
        bf16x8 rah[2], ral[2];
        float4 rw0[2], rw1[2];
        #pragma unroll
        for (int s = 0; s < 2; ++s) {
            rah[s] = xp[s * 128];
            ral[s] = xp[s * 128 + 64];
            rw0[s] = wp[s * 128];
            rw1[s] = wp[s * 128 + 64];
        }
        #pragma unroll
        for (int s = 0; s < 9; ++s) {
            bf16x8 ah = rah[s & 1], al = ral[s & 1];
            float4 w0 = rw0[s & 1], w1 = rw1[s & 1];
            if (s + 2 < 9) {
                rah[s & 1] = xp[(s + 2) * 128];
                ral[s & 1] = xp[(s + 2) * 128 + 64];
                rw0[s & 1] = wp[(s + 2) * 128];
                rw1[s & 1] = wp[(s + 2) * 128 + 64];
            }
            // i_local = (kc-kb*2)*72 + 4*s_glob + q
            float cs = (iter == 0) ? 0.1f
                                   : c_lds[(w >> 1) * 72 + 4 * (sbase + s) + q];
            float wvv[8] = {w0.x, w0.y, w0.z, w0.w, w1.x, w1.y, w1.z, w1.w};
            bf16x8 bh, bl;
            #pragma unroll
            for (int e = 0; e < 8; ++e) {
                float pe = wvv[e] * cs;
                __bf16 g = (__bf16)pe;
                bh[e] = g;
                bl[e] = (__bf16)(pe - (float)g);
            }
            acc = __builtin_amdgcn_mfma_f32_16x16x32_bf16(ah, bh, acc, 0, 0, 0);
            acc = __builtin_amdgcn_mfma_f32_16x16x32_bf16(al, bh, acc, 0, 0, 0);
            acc = __builtin_amdgcn_mfma_f32_16x16x32_bf16(ah, bl, acc, 0, 0, 0);
        }
        part[w * 64 + lane] = acc;
    }
    __syncthreads();

    // ---- in-block 4-wave reduce -> plain store of 16x16 partial, exit ----
    const int row = tid >> 4;              // 0..15 (b_local)
    const int o   = tid & 15;              // 0..15
    const int lane_c = ((row >> 2) << 4) | o;   // C/D: col=lane&15, row=quad*4+reg
    const int reg    = row & 3;
    float v = part[0 * 64 + lane_c][reg] + part[1 * 64 + lane_c][reg]
            + part[2 * 64 + lane_c][reg] + part[3 * 64 + lane_c][reg];
    pbuf[(size_t)blk * 256 + row * 16 + o] = v;
}

// ---------------------------------------------------------------------------
// B: reduce 8 k-slice partials per tile + squash + emit.
// ---------------------------------------------------------------------------
__global__ __launch_bounds__(256)
void reduce_squash_kernel(const float* __restrict__ pbuf, float* __restrict__ s_out,
                          ushort_t* __restrict__ Sbt_hi, ushort_t* __restrict__ Sbt_lo,
                          const int iter)
{
    const int tile = blockIdx.x;           // 0..159 (tile = nt*16+mb)
    const int mb   = tile & 15;
    const int nt   = tile >> 4;
    const int t    = threadIdx.x;          // 0..255
    const int row  = t >> 4;               // 0..15 (b_local)
    const int o    = t & 15;               // 0..15

    const float* pb = pbuf + (size_t)tile * 8 * 256 + row * 16 + o;
    float v = 0.f;
    #pragma unroll
    for (int u = 0; u < 8; ++u)
        v += pb[u * 256];

    float sq = v * v;
    #pragma unroll
    for (int off = 1; off < 16; off <<= 1)  // 16 consecutive lanes = one b row
        sq += __shfl_xor(sq, off, 16);
    float l2 = sqrtf(sq);
    float val = v * (l2 / (1.f + sq));
    const int b  = mb * 16 + row;
    const int jo = nt * 16 + o;
    if (iter == 2) {
        s_out[(size_t)b * N_ + jo] = val;
    } else {
        ushort_t hi = f2bf(val);
        Sbt_hi[(size_t)jo * B_ + b] = hi;
        Sbt_lo[(size_t)jo * B_ + b] = f2bf(val - bf2f(hi));
    }
}

// ---------------------------------------------------------------------------
// C: b-update GEMM (plain loads/stores only).
// ---------------------------------------------------------------------------
__global__ __launch_bounds__(256)
void gemm_bupd_kernel(const float* __restrict__ x,
                      const ushort_t* __restrict__ Sbt_hi, const ushort_t* __restrict__ Sbt_lo,
                      const float* __restrict__ W, float* __restrict__ blog,
                      const int first)
{
    // bijective remap: XCD (blk&7) gets wv in [xcd*360, xcd*360+360) -> mt
    // in [xcd*72, xcd*72+72) contiguous (720 blocks, 720%8==0).
    int wv   = (blockIdx.x & 7) * 360 + (blockIdx.x >> 3) * 4 + (threadIdx.x >> 6);
    int lane = threadIdx.x & 63;
    int mt = wv / 5;                                  // 0..575
    int jp = wv - mt * 5;                             // j-pair: j0=2jp, j1=2jp+1
    int j0 = jp * 2, j1 = jp * 2 + 1;
    int r = lane & 15, q = lane >> 4;
    const float* xp = x + (size_t)(8 * q) * K_ + (mt * 16 + r);   // + (s*32+e)*K_
    size_t b0off = (size_t)(j0 * 16 + r) * B_ + 8 * q;
    size_t b1off = (size_t)(j1 * 16 + r) * B_ + 8 * q;
    floatx4 acc0 = {0.f, 0.f, 0.f, 0.f};
    floatx4 acc1 = {0.f, 0.f, 0.f, 0.f};

    float xcur[8], xnxt[8];
    #pragma unroll
    for (int e = 0; e < 8; ++e) xcur[e] = xp[(size_t)e * K_];
    #pragma unroll
    for (int s = 0; s < B_ / 32; ++s) {
        if (s + 1 < B_ / 32) {               // prefetch next step's x column slice
            #pragma unroll
            for (int e = 0; e < 8; ++e)
                xnxt[e] = xp[(size_t)((s + 1) * 32 + e) * K_];
        }
        bf16x8 ah, al;
        #pragma unroll
        for (int e = 0; e < 8; ++e) {
            float v = xcur[e];
            __bf16 h = (__bf16)v;
            ah[e] = h;
            al[e] = (__bf16)(v - (float)h);
        }
        bf16x8 bh0 = *(const bf16x8*)(Sbt_hi + b0off + s * 32);
        bf16x8 bl0 = *(const bf16x8*)(Sbt_lo + b0off + s * 32);
        bf16x8 bh1 = *(const bf16x8*)(Sbt_hi + b1off + s * 32);
        bf16x8 bl1 = *(const bf16x8*)(Sbt_lo + b1off + s * 32);
        acc0 = __builtin_amdgcn_mfma_f32_16x16x32_bf16(ah, bh0, acc0, 0, 0, 0);
        acc0 = __builtin_amdgcn_mfma_f32_16x16x32_bf16(al, bh0, acc0, 0, 0, 0);
        acc0 = __builtin_amdgcn_mfma_f32_16x16x32_bf16(ah, bl0, acc0, 0, 0, 0);
        acc1 = __builtin_amdgcn_mfma_f32_16x16x32_bf16(ah, bh1, acc1, 0, 0, 0);
        acc1 = __builtin_amdgcn_mfma_f32_16x16x32_bf16(al, bh1, acc1, 0, 0, 0);
        acc1 = __builtin_amdgcn_mfma_f32_16x16x32_bf16(ah, bl1, acc1, 0, 0, 0);
        #pragma unroll
        for (int e = 0; e < 8; ++e) xcur[e] = xnxt[e];
    }
    // rows q*4+reg -> i = mt*2 + (q>>1), d = (q&1)*4 + reg; col -> o = lane&15
    int i  = mt * 2 + (q >> 1);
    int d0 = (q & 1) * 4;
    int o  = lane & 15;
    int iw = mt * 2 + (lane >> 5);
    {
        const float4 w4 = *(const float4*)(W + ((((size_t)i * J_ + j0) * DOUT_ + o) * DIN_ + d0));
        float val = acc0[0] * w4.x + acc0[1] * w4.y + acc0[2] * w4.z + acc0[3] * w4.w;
        #pragma unroll
        for (int off = 1; off < 32; off <<= 1)
            val += __shfl_xor(val, off, 32);
        if ((lane & 31) == 0) {
            float* dst = blog + (size_t)iw * J_ + j0;
            if (first) *dst = val; else *dst += val;
        }
    }
    {
        const float4 w4 = *(const float4*)(W + ((((size_t)i * J_ + j1) * DOUT_ + o) * DIN_ + d0));
        float val = acc1[0] * w4.x + acc1[1] * w4.y + acc1[2] * w4.z + acc1[3] * w4.w;
        #pragma unroll
        for (int off = 1; off < 32; off <<= 1)
            val += __shfl_xor(val, off, 32);
        if ((lane & 31) == 0) {
            float* dst = blog + (size_t)iw * J_ + j1;
            if (first) *dst = val; else *dst += val;
        }
    }
}

// ---------------------------------------------------------------------------
// Final configuration (session best, 135.5 us): prep, A0, B0, C0, A1, B1,
// C1, A2, B2. Kernel-boundary coherence only (measured cheapest on gfx950).
// ---------------------------------------------------------------------------
extern "C" void kernel_launch(void* const* d_in, const int* in_sizes, int n_in,
                              void* d_out, int out_size, void* d_ws, size_t ws_size,
                              hipStream_t stream)
{
    const float* x = (const float*)d_in[0];   // [B, I, DIN]
    const float* W = (const float*)d_in[1];   // [I, J, DOUT, DIN]
    float* s_out = (float*)d_out;             // [B, J, DOUT]

    char* ws = (char*)d_ws;
    ushort_t* Sbt_hi = (ushort_t*)(ws);                 //    81,920 B
    ushort_t* Sbt_lo = (ushort_t*)(ws + 81920);         //    81,920 B
    float*    blog   = (float*)   (ws + 163840);        //    46,080 B
    float*    pbuf   = (float*)   (ws + 262144);        // 1,310,720 B
    ushort_t* xPk    = (ushort_t*)(ws + 1572864);       // 9,699,328 B
    float*    wPk    = (float*)   (ws + 11272192);      // 6,062,080 B (~17.3 MB)

    prep_all_kernel<<<2592, 256, 0, stream>>>(x, W, xPk, wPk);

    for (int it = 0; it < 3; ++it) {
        gemm_s_part_kernel<<<1280, 256, 0, stream>>>(xPk, wPk, blog, pbuf, it);
        reduce_squash_kernel<<<160, 256, 0, stream>>>(pbuf, s_out,
                                                      Sbt_hi, Sbt_lo, it);
        if (it < 2)
            gemm_bupd_kernel<<<720, 256, 0, stream>>>(x, Sbt_hi, Sbt_lo,
                                                      W, blog, it == 0 ? 1 : 0);
    }
}